// Round 2
// baseline (535.775 us; speedup 1.0000x reference)
//
#include <hip/hip_runtime.h>
#include <hip/hip_cooperative_groups.h>
#include <cmath>

namespace cg = cooperative_groups;

#define NOBJ 256
#define CNUM 151
#define DDIM 512
#define NBLK 256
#define NTHR 256

// LDS staging strides ([k][m] layout, padded)
#define SAS 36
#define SBS 68

__device__ __forceinline__ float sigf(float x) { return 1.0f / (1.0f + __expf(-x)); }

// ---------------------------------------------------------------------------
// One 64-deep-K-chunk GEMM tile: acc[m][j] = sum_k fa(m,k)*fb(j,k), epilogue fe.
// 256 threads. BM<=32, BN<=64, K multiple of 64. TM*TN == BM*BN/256.
// ---------------------------------------------------------------------------
template <int BM, int BN, int TM, int TN, class FA, class FB, class FE>
__device__ __forceinline__ void gemm_tile(float* __restrict__ sA, float* __restrict__ sB,
                                          int m0, int n0, int K, FA fa, FB fb, FE fe) {
  const int t = threadIdx.x;
  const int lc = t & 63;   // k within chunk
  const int lr = t >> 6;   // wave id
  const int tm = (t & (BM / TM - 1)) * TM;
  const int tn = (t / (BM / TM)) * TN;
  float acc[TM][TN];
#pragma unroll
  for (int i = 0; i < TM; ++i)
#pragma unroll
    for (int j = 0; j < TN; ++j) acc[i][j] = 0.f;

  for (int k0 = 0; k0 < K; k0 += 64) {
#pragma unroll
    for (int i = 0; i < BM / 4; ++i)
      sA[lc * SAS + lr * (BM / 4) + i] = fa(m0 + lr * (BM / 4) + i, k0 + lc);
#pragma unroll
    for (int i = 0; i < BN / 4; ++i)
      sB[lc * SBS + lr * (BN / 4) + i] = fb(n0 + lr * (BN / 4) + i, k0 + lc);
    __syncthreads();
#pragma unroll 4
    for (int kk = 0; kk < 64; ++kk) {
      float a[TM], b[TN];
#pragma unroll
      for (int i = 0; i < TM; ++i) a[i] = sA[kk * SAS + tm + i];
#pragma unroll
      for (int j = 0; j < TN; ++j) b[j] = sB[kk * SBS + tn + j];
#pragma unroll
      for (int i = 0; i < TM; ++i)
#pragma unroll
        for (int j = 0; j < TN; ++j) acc[i][j] = fmaf(a[i], b[j], acc[i][j]);
    }
    __syncthreads();
  }
#pragma unroll
  for (int i = 0; i < TM; ++i)
#pragma unroll
    for (int j = 0; j < TN; ++j) fe(m0 + tm + i, n0 + tn + j, acc[i][j]);
}

// ---------------------------------------------------------------------------
// Persistent cooperative kernel: whole GGNN forward in one dispatch.
// Math (uniform matrix, c-uniform hidden — exact collapse of the reference):
//   hw_z = H·Wsum_z^T (z=3,4,5), hu3 = H·w3u^T + b3u
//   svh_z[j] = sum_m hw_z[m,j]  ( == sum_k S[k]·Wsum_z[j,k] )
//   gate_z[m,j] = fac·(svh_z[j] − hw_z[m,j]) + b_zw[j]
//   zv = σ(gate3+hu3), rv = σ(gate4+hu3)  [ref bug: eq4 reuses w3u/b3u]
//   hv = tanh(gate5 + (rv⊙H)·w5u^T + b5u);  Hn = (1−zv)H + zv·hv
//   O = relu([H|X]·wo^T + bo);  obj = O·Wcs^T + bc, Wcs[co,d] = Σ_c wc[co,c·D+d]
// ---------------------------------------------------------------------------
__global__ void __launch_bounds__(NTHR) ggnn_persistent(
    const float* __restrict__ X, const float* __restrict__ mat,
    const float* __restrict__ w3w, const float* __restrict__ b3w,
    const float* __restrict__ w3u, const float* __restrict__ b3u,
    const float* __restrict__ w4w, const float* __restrict__ b4w,
    const float* __restrict__ w5w, const float* __restrict__ b5w,
    const float* __restrict__ w5u, const float* __restrict__ b5u,
    const float* __restrict__ wo, const float* __restrict__ bo,
    const float* __restrict__ wc, const float* __restrict__ bc,
    float* __restrict__ out, float* __restrict__ ws) {
  cg::grid_group grid = cg::this_grid();
  __shared__ __align__(16) float smem[2304 + 4352 + 256];
  float* sA = smem;
  float* sB = smem + 2304;
  float* sred = smem + 2304 + 4352;

  float* Wsum = ws;                  // 3*512*512
  float* Wcs = Wsum + 786432;        // 151*512
  float* H0 = Wcs + 77312;           // 256*512
  float* H1 = H0 + 131072;           // 256*512
  float* hw = H1 + 131072;           // 3*256*512 (hw3,hw4,hw5)
  float* hu3 = hw + 393216;          // 256*512
  float* svh = hu3 + 131072;         // 3*512
  float* O = svh + 1536;             // 256*512

  const int blk = blockIdx.x;
  const int t = threadIdx.x;
  const int gtid = blk * NTHR + t;
  const float fac = mat[0] * (float)CNUM;

  // ---- P: Wsum (fold the [av1,av2] concat) + Wcs (fold c-uniformity of out) ----
  for (int idx = gtid; idx < 3 * DDIM * DDIM; idx += NBLK * NTHR) {
    int z = idx >> 18, r = idx & (DDIM * DDIM - 1);
    int j = r >> 9, k = r & 511;
    const float* w = (z == 0) ? w3w : (z == 1) ? w4w : w5w;
    Wsum[idx] = w[j * 1024 + k] + w[j * 1024 + 512 + k];
  }
  for (int idx = gtid; idx < CNUM * DDIM; idx += NBLK * NTHR) {
    int co = idx >> 9, d = idx & 511;
    const float* row = wc + (size_t)co * (CNUM * DDIM);
    float s = 0.f;
    for (int c = 0; c < CNUM; ++c) s += row[c * DDIM + d];
    Wcs[idx] = s;
  }
  grid.sync();

  const float* Hc = X;  // t=0 hidden is the (c-uniform) input broadcast
  float* Hn = H0;
  for (int it = 0; it < 3; ++it) {
    // ---- G1: hw_z (raw) and hu3, as one 256-tile GEMM sweep ----
    {
      const int z = blk >> 6;          // 0..3
      const int tl = blk & 63;
      const int m0 = (tl >> 3) * 32;   // 8 m-tiles of 32
      const int n0 = (tl & 7) * 64;    // 8 n-tiles of 64
      const float* B = (z < 3) ? (Wsum + z * DDIM * DDIM) : w3u;
      float* op = (z < 3) ? (hw + z * 131072) : hu3;
      auto fa = [&](int m, int k) { return Hc[m * DDIM + k]; };
      auto fb = [&](int j, int k) { return B[j * DDIM + k]; };
      auto fe = [&](int m, int j, float a) {
        op[m * DDIM + j] = (z == 3) ? (a + b3u[j]) : a;
      };
      gemm_tile<32, 64, 2, 4>(sA, sB, m0, n0, DDIM, fa, fb, fe);
    }
    grid.sync();
    // ---- CS: svh_z[j] = column sums of hw_z ----
    if (blk < 192) {
      const int z = blk >> 6, cc = blk & 63;  // 8 cols per block
      const float* hwz = hw + z * 131072;
      const int col = cc * 8 + (t & 7);
      const int r0 = (t >> 3) * 8;
      float s = 0.f;
#pragma unroll
      for (int i = 0; i < 8; ++i) s += hwz[(r0 + i) * DDIM + col];
      sred[t] = s;
      __syncthreads();
      for (int off = 128; off >= 8; off >>= 1) {
        if (t < off) sred[t] += sred[t + off];
        __syncthreads();
      }
      if (t < 8) svh[z * DDIM + cc * 8 + t] = sred[t];
    }
    grid.sync();
    // ---- G2: (rv⊙H)·w5u^T with full GRU update fused in the epilogue ----
    {
      const int m0 = (blk >> 4) * 16;
      const int n0 = (blk & 15) * 32;
      const float* hw3 = hw;
      const float* hw4 = hw + 131072;
      const float* hw5 = hw + 262144;
      auto fa = [&](int m, int k) {
        int idx = m * DDIM + k;
        float rv = sigf(fac * (svh[DDIM + k] - hw4[idx]) + b4w[k] + hu3[idx]);
        return rv * Hc[idx];
      };
      auto fb = [&](int j, int k) { return w5u[j * DDIM + k]; };
      auto fe = [&](int m, int j, float a) {
        int idx = m * DDIM + j;
        float a5 = fac * (svh[2 * DDIM + j] - hw5[idx]) + b5w[j];
        float hv = tanhf(a5 + a + b5u[j]);
        float zv = sigf(fac * (svh[j] - hw3[idx]) + b3w[j] + hu3[idx]);
        Hn[idx] = (1.f - zv) * Hc[idx] + zv * hv;
      };
      gemm_tile<16, 32, 1, 2>(sA, sB, m0, n0, DDIM, fa, fb, fe);
    }
    grid.sync();
    Hc = Hn;
    Hn = (Hc == H0) ? H1 : H0;
  }
  // ---- O = relu([H|X]·wo^T + bo), K=1024 ----
  {
    const int m0 = (blk >> 4) * 16;
    const int n0 = (blk & 15) * 32;
    auto fa = [&](int m, int k) {
      return (k < DDIM) ? Hc[m * DDIM + k] : X[m * DDIM + (k - DDIM)];
    };
    auto fb = [&](int j, int k) { return wo[j * 2 * DDIM + k]; };
    auto fe = [&](int m, int j, float a) { O[m * DDIM + j] = fmaxf(a + bo[j], 0.f); };
    gemm_tile<16, 32, 1, 2>(sA, sB, m0, n0, 2 * DDIM, fa, fb, fe);
  }
  grid.sync();
  // ---- obj = O·Wcs^T + bc  (N=151, padded to 160) ----
  if (blk < 80) {
    const int m0 = (blk / 5) * 16;
    const int n0 = (blk % 5) * 32;
    auto fa = [&](int m, int k) { return O[m * DDIM + k]; };
    auto fb = [&](int j, int k) { return (j < CNUM) ? Wcs[j * DDIM + k] : 0.f; };
    auto fe = [&](int m, int j, float a) {
      if (j < CNUM) out[m * CNUM + j] = a + bc[j];
    };
    gemm_tile<16, 32, 1, 2>(sA, sB, m0, n0, DDIM, fa, fb, fe);
  }
}

extern "C" void kernel_launch(void* const* d_in, const int* in_sizes, int n_in,
                              void* d_out, int out_size, void* d_ws, size_t ws_size,
                              hipStream_t stream) {
  const float* X = (const float*)d_in[0];
  const float* mat = (const float*)d_in[1];
  const float* w3w = (const float*)d_in[2];
  const float* b3w = (const float*)d_in[3];
  const float* w3u = (const float*)d_in[4];
  const float* b3u = (const float*)d_in[5];
  const float* w4w = (const float*)d_in[6];
  const float* b4w = (const float*)d_in[7];
  // d_in[8], d_in[9] (w4u, b4u) unused — reference reuses w3u/b3u (faithful bug)
  const float* w5w = (const float*)d_in[10];
  const float* b5w = (const float*)d_in[11];
  const float* w5u = (const float*)d_in[12];
  const float* b5u = (const float*)d_in[13];
  const float* wo = (const float*)d_in[14];
  const float* bo = (const float*)d_in[15];
  const float* wc = (const float*)d_in[16];
  const float* bc = (const float*)d_in[17];
  float* out = (float*)d_out;
  float* ws = (float*)d_ws;

  void* args[] = {(void*)&X,   (void*)&mat, (void*)&w3w, (void*)&b3w, (void*)&w3u,
                  (void*)&b3u, (void*)&w4w, (void*)&b4w, (void*)&w5w, (void*)&b5w,
                  (void*)&w5u, (void*)&b5u, (void*)&wo,  (void*)&bo,  (void*)&wc,
                  (void*)&bc,  (void*)&out, (void*)&ws};
  hipLaunchCooperativeKernel((const void*)ggnn_persistent, dim3(NBLK), dim3(NTHR),
                             args, 0, stream);
}

// Round 3
// 190.109 us; speedup vs baseline: 2.8183x; 2.8183x over previous
//
#include <hip/hip_runtime.h>
#include <cmath>

constexpr int NOBJ = 256, CNUM = 151, DDIM = 512;

__device__ __forceinline__ float sigf(float x) { return 1.0f / (1.0f + __expf(-x)); }
__device__ __forceinline__ float tanhf_(float x) {
  float e = __expf(-2.0f * fabsf(x));
  float y = (1.0f - e) / (1.0f + e);
  return copysignf(y, x);
}

// ---------------------------------------------------------------------------
// Wcs[co][d] = sum_c wc[co][c*512+d]  (collapse of c-uniform output concat)
// 151 blocks x 256 thr; each block streams 309 KB coalesced.
// ---------------------------------------------------------------------------
__global__ void __launch_bounds__(256) k_wcs(const float* __restrict__ wc,
                                             float* __restrict__ Wcs) {
  const int co = blockIdx.x, t = threadIdx.x;
  const float* row = wc + (size_t)co * (CNUM * DDIM);
  const int dq = (t & 127) * 4, half = t >> 7;
  float4 s = make_float4(0.f, 0.f, 0.f, 0.f);
#pragma unroll 4
  for (int c = half; c < CNUM; c += 2) {
    const float4 v = *reinterpret_cast<const float4*>(row + c * DDIM + dq);
    s.x += v.x; s.y += v.y; s.z += v.z; s.w += v.w;
  }
  __shared__ float4 red[128];
  if (half) red[t & 127] = s;
  __syncthreads();
  if (!half) {
    float4 o = red[t];
    o.x += s.x; o.y += s.y; o.z += s.z; o.w += s.w;
    *reinterpret_cast<float4*>(Wcs + co * DDIM + dq) = o;
  }
}

// ---------------------------------------------------------------------------
// G1: hw_z = H * Wsum_z^T (z=0,1,2 folded on the fly), hu3 = H*w3u^T + b3u.
// N flattened to 4*512. Tile 16x128, 256 thr, micro 2x4. grid (16,16)=256.
// Epilogue: deterministic column partials psum[z][mtile][512] via shfl reduce.
// ---------------------------------------------------------------------------
__global__ void __launch_bounds__(256) k_G1(
    const float* __restrict__ H, const float* __restrict__ w3w,
    const float* __restrict__ w4w, const float* __restrict__ w5w,
    const float* __restrict__ w3u, const float* __restrict__ b3u,
    float* __restrict__ hw, float* __restrict__ psum) {
  __shared__ float sA[64 * 18];   // [k][m], 16 rows, pad 18 (8B align for float2)
  __shared__ float sB[64 * 132];  // [k][j], 128 cols, pad 132 (16B align for float4)
  const int t = threadIdx.x;
  const int m0 = blockIdx.x * 16;
  const int p = blockIdx.y;
  const int z = p >> 2;
  const int j0 = (p & 3) * 128;
  const float* W = (z == 0) ? w3w : (z == 1) ? w4w : (z == 2) ? w5w : w3u;
  const int ar = t >> 4, ak = (t & 15) * 4;
  const int bj = t >> 4, bk = (t & 15) * 4;
  const int tm = (t & 7) * 2, tn = (t >> 3) * 4;
  float acc[2][4] = {{0, 0, 0, 0}, {0, 0, 0, 0}};

  for (int k0 = 0; k0 < DDIM; k0 += 64) {
    {
      const float4 v = *reinterpret_cast<const float4*>(H + (m0 + ar) * DDIM + k0 + ak);
      sA[(ak + 0) * 18 + ar] = v.x; sA[(ak + 1) * 18 + ar] = v.y;
      sA[(ak + 2) * 18 + ar] = v.z; sA[(ak + 3) * 18 + ar] = v.w;
    }
    if (z < 3) {
#pragma unroll
      for (int i = 0; i < 8; ++i) {
        const int j = j0 + i * 16 + bj;
        const float* base = W + (size_t)j * 1024 + k0 + bk;
        const float4 a1 = *reinterpret_cast<const float4*>(base);
        const float4 a2 = *reinterpret_cast<const float4*>(base + 512);
        const int jl = i * 16 + bj;
        sB[(bk + 0) * 132 + jl] = a1.x + a2.x; sB[(bk + 1) * 132 + jl] = a1.y + a2.y;
        sB[(bk + 2) * 132 + jl] = a1.z + a2.z; sB[(bk + 3) * 132 + jl] = a1.w + a2.w;
      }
    } else {
#pragma unroll
      for (int i = 0; i < 8; ++i) {
        const int j = j0 + i * 16 + bj;
        const float4 v = *reinterpret_cast<const float4*>(W + (size_t)j * 512 + k0 + bk);
        const int jl = i * 16 + bj;
        sB[(bk + 0) * 132 + jl] = v.x; sB[(bk + 1) * 132 + jl] = v.y;
        sB[(bk + 2) * 132 + jl] = v.z; sB[(bk + 3) * 132 + jl] = v.w;
      }
    }
    __syncthreads();
#pragma unroll 8
    for (int kk = 0; kk < 64; ++kk) {
      const float2 a = *reinterpret_cast<const float2*>(sA + kk * 18 + tm);
      const float4 b = *reinterpret_cast<const float4*>(sB + kk * 132 + tn);
      acc[0][0] = fmaf(a.x, b.x, acc[0][0]); acc[0][1] = fmaf(a.x, b.y, acc[0][1]);
      acc[0][2] = fmaf(a.x, b.z, acc[0][2]); acc[0][3] = fmaf(a.x, b.w, acc[0][3]);
      acc[1][0] = fmaf(a.y, b.x, acc[1][0]); acc[1][1] = fmaf(a.y, b.y, acc[1][1]);
      acc[1][2] = fmaf(a.y, b.z, acc[1][2]); acc[1][3] = fmaf(a.y, b.w, acc[1][3]);
    }
    __syncthreads();
  }

  float* op = hw + z * (NOBJ * DDIM);
  float4 bias = make_float4(0.f, 0.f, 0.f, 0.f);
  if (z == 3) bias = *reinterpret_cast<const float4*>(b3u + j0 + tn);
#pragma unroll
  for (int i = 0; i < 2; ++i) {
    const float4 r = make_float4(acc[i][0] + bias.x, acc[i][1] + bias.y,
                                 acc[i][2] + bias.z, acc[i][3] + bias.w);
    *reinterpret_cast<float4*>(op + (m0 + tm + i) * DDIM + j0 + tn) = r;
  }
  if (z < 3) {  // column partial sums over this block's 16 rows (deterministic)
    float s0 = acc[0][0] + acc[1][0], s1 = acc[0][1] + acc[1][1];
    float s2 = acc[0][2] + acc[1][2], s3 = acc[0][3] + acc[1][3];
#pragma unroll
    for (int m = 1; m < 8; m <<= 1) {
      s0 += __shfl_xor(s0, m, 64); s1 += __shfl_xor(s1, m, 64);
      s2 += __shfl_xor(s2, m, 64); s3 += __shfl_xor(s3, m, 64);
    }
    if ((t & 7) == 0)
      *reinterpret_cast<float4*>(psum + z * 8192 + blockIdx.x * 512 + j0 + tn) =
          make_float4(s0, s1, s2, s3);
  }
}

// ---------------------------------------------------------------------------
// G2: per 8-row band: svh from psum; rv=sig(fac(svh4-hw4)+b4w+hu3); rvH in LDS;
// (rvH)*w5u^T; epilogue = full GRU update -> Hn. Tile 8x64. grid (32,8)=256.
// ---------------------------------------------------------------------------
__global__ void __launch_bounds__(256) k_G2(
    const float* __restrict__ H, const float* __restrict__ hw,
    const float* __restrict__ psum, const float* __restrict__ mat,
    const float* __restrict__ b3w, const float* __restrict__ b4w,
    const float* __restrict__ b5w, const float* __restrict__ w5u,
    const float* __restrict__ b5u, float* __restrict__ Hn) {
  __shared__ float sA[DDIM * 9];  // rv*H, [k][m], 8 rows pad 9, full K resident
  __shared__ float sB[64 * 68];   // w5u chunk [k][j]
  __shared__ float sv4[DDIM];
  __shared__ float sv35[128];
  const int t = threadIdx.x;
  const int m0 = blockIdx.x * 8;
  const int j0 = blockIdx.y * 64;
  const float fac = mat[0] * (float)CNUM;
  const float* hw3 = hw;
  const float* hw4 = hw + NOBJ * DDIM;
  const float* hw5 = hw + 2 * NOBJ * DDIM;
  const float* hu3 = hw + 3 * NOBJ * DDIM;

  {  // svh4 (all 512 cols) = sum_mt psum[1][mt][:]
    const int k2 = t * 2;
    float a = 0.f, b = 0.f;
#pragma unroll
    for (int mt = 0; mt < 16; ++mt) {
      const float2 v = *reinterpret_cast<const float2*>(psum + 8192 + mt * 512 + k2);
      a += v.x; b += v.y;
    }
    sv4[k2] = a; sv4[k2 + 1] = b;
  }
  if (t < 64) {  // svh3, svh5 at this block's j-panel
    const int j = j0 + t;
    float a = 0.f, b = 0.f;
#pragma unroll
    for (int mt = 0; mt < 16; ++mt) {
      a += psum[mt * 512 + j];
      b += psum[2 * 8192 + mt * 512 + j];
    }
    sv35[t] = a; sv35[64 + t] = b;
  }
  __syncthreads();

  {  // stage rv ⊙ H for the 8 rows, full K
    const int r = t >> 5;
    const int kb = (t & 31) * 4;
#pragma unroll
    for (int i = 0; i < 4; ++i) {
      const int kq = kb + i * 128;
      const int idx = (m0 + r) * DDIM + kq;
      const float4 h4 = *reinterpret_cast<const float4*>(hw4 + idx);
      const float4 u3 = *reinterpret_cast<const float4*>(hu3 + idx);
      const float4 hh = *reinterpret_cast<const float4*>(H + idx);
      const float4 b4 = *reinterpret_cast<const float4*>(b4w + kq);
      const float4 s4 = *reinterpret_cast<const float4*>(sv4 + kq);
      sA[(kq + 0) * 9 + r] = sigf(fac * (s4.x - h4.x) + b4.x + u3.x) * hh.x;
      sA[(kq + 1) * 9 + r] = sigf(fac * (s4.y - h4.y) + b4.y + u3.y) * hh.y;
      sA[(kq + 2) * 9 + r] = sigf(fac * (s4.z - h4.z) + b4.z + u3.z) * hh.z;
      sA[(kq + 3) * 9 + r] = sigf(fac * (s4.w - h4.w) + b4.w + u3.w) * hh.w;
    }
  }

  const int tm = t & 7, tn = (t >> 3) * 2;
  float acc0 = 0.f, acc1 = 0.f;
  for (int k0 = 0; k0 < DDIM; k0 += 64) {
    __syncthreads();
    {
      const int bj = t >> 4, bk = (t & 15) * 4;
#pragma unroll
      for (int i = 0; i < 4; ++i) {
        const int j = bj + i * 16;
        const float4 v =
            *reinterpret_cast<const float4*>(w5u + (size_t)(j0 + j) * DDIM + k0 + bk);
        sB[(bk + 0) * 68 + j] = v.x; sB[(bk + 1) * 68 + j] = v.y;
        sB[(bk + 2) * 68 + j] = v.z; sB[(bk + 3) * 68 + j] = v.w;
      }
    }
    __syncthreads();
#pragma unroll 8
    for (int kk = 0; kk < 64; ++kk) {
      const float a = sA[(k0 + kk) * 9 + tm];
      const float2 b = *reinterpret_cast<const float2*>(sB + kk * 68 + tn);
      acc0 = fmaf(a, b.x, acc0);
      acc1 = fmaf(a, b.y, acc1);
    }
  }

  const int m = m0 + tm;
  float res[2];
#pragma unroll
  for (int jj = 0; jj < 2; ++jj) {
    const int j = j0 + tn + jj;
    const int idx = m * DDIM + j;
    const float a = (jj == 0) ? acc0 : acc1;
    const float hv = tanhf_(fac * (sv35[64 + tn + jj] - hw5[idx]) + b5w[j] + a + b5u[j]);
    const float zv = sigf(fac * (sv35[tn + jj] - hw3[idx]) + b3w[j] + hu3[idx]);
    const float hp = H[idx];
    res[jj] = (1.f - zv) * hp + zv * hv;
  }
  *reinterpret_cast<float2*>(Hn + m * DDIM + j0 + tn) = make_float2(res[0], res[1]);
}

// ---------------------------------------------------------------------------
// O = relu([H|X]*wo^T + bo). Tile 8x64, K=1024. grid (32,8)=256.
// ---------------------------------------------------------------------------
__global__ void __launch_bounds__(256) k_out(const float* __restrict__ H,
                                             const float* __restrict__ X,
                                             const float* __restrict__ wo,
                                             const float* __restrict__ bo,
                                             float* __restrict__ O) {
  __shared__ float sA[64 * 9];
  __shared__ float sB[64 * 68];
  const int t = threadIdx.x;
  const int m0 = blockIdx.x * 8;
  const int j0 = blockIdx.y * 64;
  const int tm = t & 7, tn = (t >> 3) * 2;
  float acc0 = 0.f, acc1 = 0.f;
  for (int k0 = 0; k0 < 2 * DDIM; k0 += 64) {
    __syncthreads();
    {
      const int r = t >> 5, kp = (t & 31) * 2;
      const float* src = (k0 < DDIM) ? (H + (m0 + r) * DDIM + k0 + kp)
                                     : (X + (m0 + r) * DDIM + (k0 - DDIM) + kp);
      const float2 v = *reinterpret_cast<const float2*>(src);
      sA[(kp + 0) * 9 + r] = v.x; sA[(kp + 1) * 9 + r] = v.y;
      const int bj = t >> 4, bk = (t & 15) * 4;
#pragma unroll
      for (int i = 0; i < 4; ++i) {
        const int j = bj + i * 16;
        const float4 v2 =
            *reinterpret_cast<const float4*>(wo + (size_t)(j0 + j) * 1024 + k0 + bk);
        sB[(bk + 0) * 68 + j] = v2.x; sB[(bk + 1) * 68 + j] = v2.y;
        sB[(bk + 2) * 68 + j] = v2.z; sB[(bk + 3) * 68 + j] = v2.w;
      }
    }
    __syncthreads();
#pragma unroll 8
    for (int kk = 0; kk < 64; ++kk) {
      const float a = sA[kk * 9 + tm];
      const float2 b = *reinterpret_cast<const float2*>(sB + kk * 68 + tn);
      acc0 = fmaf(a, b.x, acc0); acc1 = fmaf(a, b.y, acc1);
    }
  }
  const int j = j0 + tn;
  *reinterpret_cast<float2*>(O + (m0 + tm) * DDIM + j) =
      make_float2(fmaxf(acc0 + bo[j], 0.f), fmaxf(acc1 + bo[j + 1], 0.f));
}

// ---------------------------------------------------------------------------
// obj = O*Wcs^T + bc. Tile 8x32 (N=151 guarded). grid (32,5)=160.
// ---------------------------------------------------------------------------
__global__ void __launch_bounds__(256) k_obj(const float* __restrict__ O,
                                             const float* __restrict__ Wcs,
                                             const float* __restrict__ bc,
                                             float* __restrict__ out) {
  __shared__ float sA[64 * 9];
  __shared__ float sB[64 * 36];
  const int t = threadIdx.x;
  const int m0 = blockIdx.x * 8;
  const int j0 = blockIdx.y * 32;
  const int tm = t & 7, tn = t >> 3;
  float acc = 0.f;
  for (int k0 = 0; k0 < DDIM; k0 += 64) {
    __syncthreads();
    {
      const int r = t >> 5, kp = (t & 31) * 2;
      const float2 v = *reinterpret_cast<const float2*>(O + (m0 + r) * DDIM + k0 + kp);
      sA[(kp + 0) * 9 + r] = v.x; sA[(kp + 1) * 9 + r] = v.y;
      const int bj = t >> 4, bk = (t & 15) * 4;
#pragma unroll
      for (int i = 0; i < 2; ++i) {
        const int j = bj + i * 16;
        const int jg = j0 + j;
        float4 v2 = make_float4(0.f, 0.f, 0.f, 0.f);
        if (jg < CNUM)
          v2 = *reinterpret_cast<const float4*>(Wcs + (size_t)jg * DDIM + k0 + bk);
        sB[(bk + 0) * 36 + j] = v2.x; sB[(bk + 1) * 36 + j] = v2.y;
        sB[(bk + 2) * 36 + j] = v2.z; sB[(bk + 3) * 36 + j] = v2.w;
      }
    }
    __syncthreads();
#pragma unroll 8
    for (int kk = 0; kk < 64; ++kk)
      acc = fmaf(sA[kk * 9 + tm], sB[kk * 36 + tn], acc);
  }
  const int jg = j0 + tn;
  if (jg < CNUM) out[(m0 + tm) * CNUM + jg] = acc + bc[jg];
}

extern "C" void kernel_launch(void* const* d_in, const int* in_sizes, int n_in,
                              void* d_out, int out_size, void* d_ws, size_t ws_size,
                              hipStream_t stream) {
  const float* X = (const float*)d_in[0];
  const float* mat = (const float*)d_in[1];
  const float* w3w = (const float*)d_in[2];
  const float* b3w = (const float*)d_in[3];
  const float* w3u = (const float*)d_in[4];
  const float* b3u = (const float*)d_in[5];
  const float* w4w = (const float*)d_in[6];
  const float* b4w = (const float*)d_in[7];
  // d_in[8], d_in[9] (w4u, b4u) unused — reference reuses w3u/b3u (faithful bug)
  const float* w5w = (const float*)d_in[10];
  const float* b5w = (const float*)d_in[11];
  const float* w5u = (const float*)d_in[12];
  const float* b5u = (const float*)d_in[13];
  const float* wo = (const float*)d_in[14];
  const float* bo = (const float*)d_in[15];
  const float* wc = (const float*)d_in[16];
  const float* bc = (const float*)d_in[17];
  float* out = (float*)d_out;
  float* ws = (float*)d_ws;

  // workspace (floats): ~3.9 MB
  float* Wcs = ws;                 // 151*512      = 77312
  float* hw = Wcs + 77312;         // 4*256*512    = 524288 (hw3,hw4,hw5,hu3)
  float* psum = hw + 524288;       // 3*16*512     = 24576
  float* H0 = psum + 24576;        // 131072
  float* H1 = H0 + 131072;         // 131072
  float* Obuf = H1 + 131072;       // 131072

  k_wcs<<<CNUM, 256, 0, stream>>>(wc, Wcs);

  const float* Hc = X;  // t=0 hidden = broadcast input (c-uniform collapse)
  float* Hn = H0;
  for (int it = 0; it < 3; ++it) {
    k_G1<<<dim3(16, 16), 256, 0, stream>>>(Hc, w3w, w4w, w5w, w3u, b3u, hw, psum);
    k_G2<<<dim3(32, 8), 256, 0, stream>>>(Hc, hw, psum, mat, b3w, b4w, b5w, w5u, b5u, Hn);
    Hc = Hn;
    Hn = (Hc == H0) ? H1 : H0;
  }
  k_out<<<dim3(32, 8), 256, 0, stream>>>(Hc, X, wo, bo, Obuf);
  k_obj<<<dim3(32, 5), 256, 0, stream>>>(Obuf, Wcs, bc, out);
}

// Round 4
// 179.500 us; speedup vs baseline: 2.9848x; 1.0591x over previous
//
#include <hip/hip_runtime.h>
#include <cmath>

constexpr int NOBJ = 256, CNUM = 151, DDIM = 512;

__device__ __forceinline__ float sigf(float x) { return 1.0f / (1.0f + __expf(-x)); }
__device__ __forceinline__ float tanhf_(float x) {
  float e = __expf(-2.0f * fabsf(x));
  float y = (1.0f - e) / (1.0f + e);
  return copysignf(y, x);
}

// ---------------------------------------------------------------------------
// Wcs[co][d] = sum_c wc[co][c*512+d]  (collapse of c-uniform output concat)
// ---------------------------------------------------------------------------
__global__ void __launch_bounds__(256) k_wcs(const float* __restrict__ wc,
                                             float* __restrict__ Wcs) {
  const int co = blockIdx.x, t = threadIdx.x;
  const float* row = wc + (size_t)co * (CNUM * DDIM);
  const int dq = (t & 127) * 4, half = t >> 7;
  float4 s = make_float4(0.f, 0.f, 0.f, 0.f);
#pragma unroll 4
  for (int c = half; c < CNUM; c += 2) {
    const float4 v = *reinterpret_cast<const float4*>(row + c * DDIM + dq);
    s.x += v.x; s.y += v.y; s.z += v.z; s.w += v.w;
  }
  __shared__ float4 red[128];
  if (half) red[t & 127] = s;
  __syncthreads();
  if (!half) {
    float4 o = red[t];
    o.x += s.x; o.y += s.y; o.z += s.z; o.w += s.w;
    *reinterpret_cast<float4*>(Wcs + co * DDIM + dq) = o;
  }
}

// ---------------------------------------------------------------------------
// G1: hw_z = H * Wsum_z^T (z=0,1,2 folded on the fly), hu3 = H*w3u^T + b3u.
// Tile 32(m) x 64(j), micro 4x2, 256 thr. grid (8, 32): by -> z=by>>3, panel.
// LDS: odd-ish strides (34/66): scalar stores <=4-way, float2 reads
// conflict-free (bank = (2k+m)&31 spans 16+ banks; same-addr reads broadcast).
// Epilogue: per-m-block column partials psum[z][8][512] via shfl_xor octet.
// ---------------------------------------------------------------------------
__global__ void __launch_bounds__(256) k_G1(
    const float* __restrict__ H, const float* __restrict__ w3w,
    const float* __restrict__ w4w, const float* __restrict__ w5w,
    const float* __restrict__ w3u, const float* __restrict__ b3u,
    float* __restrict__ hw, float* __restrict__ psum) {
  __shared__ float sA[64 * 34];  // [k][32 m + 2]
  __shared__ float sB[64 * 66];  // [k][64 j + 2]
  const int t = threadIdx.x;
  const int m0 = blockIdx.x * 32;
  const int p = blockIdx.y;
  const int z = p >> 3;
  const int j0 = (p & 7) * 64;
  const float* W = (z == 0) ? w3w : (z == 1) ? w4w : (z == 2) ? w5w : w3u;
  const int am = t >> 3, ak = (t & 7) * 8;    // A-load: row am, 8 k's
  const int bj = t >> 4, bk = (t & 15) * 4;   // B-load: 4 j-rows, 4 k's
  const int tm = (t & 7) * 4, tn = (t >> 3) * 2;
  float acc[4][2] = {{0.f, 0.f}, {0.f, 0.f}, {0.f, 0.f}, {0.f, 0.f}};

  for (int k0 = 0; k0 < DDIM; k0 += 64) {
    {
      const float* src = H + (size_t)(m0 + am) * DDIM + k0 + ak;
      const float4 a0 = *reinterpret_cast<const float4*>(src);
      const float4 a1 = *reinterpret_cast<const float4*>(src + 4);
      sA[(ak + 0) * 34 + am] = a0.x; sA[(ak + 1) * 34 + am] = a0.y;
      sA[(ak + 2) * 34 + am] = a0.z; sA[(ak + 3) * 34 + am] = a0.w;
      sA[(ak + 4) * 34 + am] = a1.x; sA[(ak + 5) * 34 + am] = a1.y;
      sA[(ak + 6) * 34 + am] = a1.z; sA[(ak + 7) * 34 + am] = a1.w;
    }
    if (z < 3) {
#pragma unroll
      for (int i = 0; i < 4; ++i) {
        const int jl = bj + 16 * i;
        const float* base = W + (size_t)(j0 + jl) * 1024 + k0 + bk;
        const float4 v1 = *reinterpret_cast<const float4*>(base);
        const float4 v2 = *reinterpret_cast<const float4*>(base + 512);
        sB[(bk + 0) * 66 + jl] = v1.x + v2.x; sB[(bk + 1) * 66 + jl] = v1.y + v2.y;
        sB[(bk + 2) * 66 + jl] = v1.z + v2.z; sB[(bk + 3) * 66 + jl] = v1.w + v2.w;
      }
    } else {
#pragma unroll
      for (int i = 0; i < 4; ++i) {
        const int jl = bj + 16 * i;
        const float4 v =
            *reinterpret_cast<const float4*>(W + (size_t)(j0 + jl) * 512 + k0 + bk);
        sB[(bk + 0) * 66 + jl] = v.x; sB[(bk + 1) * 66 + jl] = v.y;
        sB[(bk + 2) * 66 + jl] = v.z; sB[(bk + 3) * 66 + jl] = v.w;
      }
    }
    __syncthreads();
#pragma unroll 8
    for (int kk = 0; kk < 64; ++kk) {
      const float2 aA = *reinterpret_cast<const float2*>(sA + kk * 34 + tm);
      const float2 aB = *reinterpret_cast<const float2*>(sA + kk * 34 + tm + 2);
      const float2 b = *reinterpret_cast<const float2*>(sB + kk * 66 + tn);
      acc[0][0] = fmaf(aA.x, b.x, acc[0][0]); acc[0][1] = fmaf(aA.x, b.y, acc[0][1]);
      acc[1][0] = fmaf(aA.y, b.x, acc[1][0]); acc[1][1] = fmaf(aA.y, b.y, acc[1][1]);
      acc[2][0] = fmaf(aB.x, b.x, acc[2][0]); acc[2][1] = fmaf(aB.x, b.y, acc[2][1]);
      acc[3][0] = fmaf(aB.y, b.x, acc[3][0]); acc[3][1] = fmaf(aB.y, b.y, acc[3][1]);
    }
    __syncthreads();
  }

  float* op = (z < 3) ? (hw + z * (NOBJ * DDIM)) : (hw + 3 * (NOBJ * DDIM));
  float2 bias = make_float2(0.f, 0.f);
  if (z == 3) bias = *reinterpret_cast<const float2*>(b3u + j0 + tn);
#pragma unroll
  for (int r = 0; r < 4; ++r) {
    const float2 o = make_float2(acc[r][0] + bias.x, acc[r][1] + bias.y);
    *reinterpret_cast<float2*>(op + (size_t)(m0 + tm + r) * DDIM + j0 + tn) = o;
  }
  if (z < 3) {  // deterministic column sums over this block's 32 rows
    float s0 = acc[0][0] + acc[1][0] + acc[2][0] + acc[3][0];
    float s1 = acc[0][1] + acc[1][1] + acc[2][1] + acc[3][1];
#pragma unroll
    for (int mask = 1; mask < 8; mask <<= 1) {
      s0 += __shfl_xor(s0, mask, 64);
      s1 += __shfl_xor(s1, mask, 64);
    }
    if ((t & 7) == 0)
      *reinterpret_cast<float2*>(psum + z * 4096 + blockIdx.x * 512 + j0 + tn) =
          make_float2(s0, s1);
  }
}

// ---------------------------------------------------------------------------
// G2: per 8-row band: svh from psum; rv=sig(fac(svh4-hw4)+b4w+hu3); rvH in LDS;
// (rvH)*w5u^T; epilogue = full GRU update -> Hn. Tile 8x64. grid (32,8)=256.
// ---------------------------------------------------------------------------
__global__ void __launch_bounds__(256) k_G2(
    const float* __restrict__ H, const float* __restrict__ hw,
    const float* __restrict__ psum, const float* __restrict__ mat,
    const float* __restrict__ b3w, const float* __restrict__ b4w,
    const float* __restrict__ b5w, const float* __restrict__ w5u,
    const float* __restrict__ b5u, float* __restrict__ Hn) {
  __shared__ float sA[DDIM * 9];  // rv*H, [k][m], 8 rows pad 9, full K resident
  __shared__ float sB[64 * 68];   // w5u chunk [k][j]
  __shared__ float sv4[DDIM];
  __shared__ float sv35[128];
  const int t = threadIdx.x;
  const int m0 = blockIdx.x * 8;
  const int j0 = blockIdx.y * 64;
  const float fac = mat[0] * (float)CNUM;
  const float* hw3 = hw;
  const float* hw4 = hw + NOBJ * DDIM;
  const float* hw5 = hw + 2 * NOBJ * DDIM;
  const float* hu3 = hw + 3 * NOBJ * DDIM;

  {  // svh4 (all 512 cols) = sum_mt psum[1][mt][:]
    const int k2 = t * 2;
    float a = 0.f, b = 0.f;
#pragma unroll
    for (int mt = 0; mt < 8; ++mt) {
      const float2 v = *reinterpret_cast<const float2*>(psum + 4096 + mt * 512 + k2);
      a += v.x; b += v.y;
    }
    sv4[k2] = a; sv4[k2 + 1] = b;
  }
  if (t < 64) {  // svh3, svh5 at this block's j-panel
    const int j = j0 + t;
    float a = 0.f, b = 0.f;
#pragma unroll
    for (int mt = 0; mt < 8; ++mt) {
      a += psum[mt * 512 + j];
      b += psum[2 * 4096 + mt * 512 + j];
    }
    sv35[t] = a; sv35[64 + t] = b;
  }
  __syncthreads();

  {  // stage rv ⊙ H for the 8 rows, full K
    const int r = t >> 5;
    const int kb = (t & 31) * 4;
#pragma unroll
    for (int i = 0; i < 4; ++i) {
      const int kq = kb + i * 128;
      const int idx = (m0 + r) * DDIM + kq;
      const float4 h4 = *reinterpret_cast<const float4*>(hw4 + idx);
      const float4 u3 = *reinterpret_cast<const float4*>(hu3 + idx);
      const float4 hh = *reinterpret_cast<const float4*>(H + idx);
      const float4 b4 = *reinterpret_cast<const float4*>(b4w + kq);
      const float4 s4 = *reinterpret_cast<const float4*>(sv4 + kq);
      sA[(kq + 0) * 9 + r] = sigf(fac * (s4.x - h4.x) + b4.x + u3.x) * hh.x;
      sA[(kq + 1) * 9 + r] = sigf(fac * (s4.y - h4.y) + b4.y + u3.y) * hh.y;
      sA[(kq + 2) * 9 + r] = sigf(fac * (s4.z - h4.z) + b4.z + u3.z) * hh.z;
      sA[(kq + 3) * 9 + r] = sigf(fac * (s4.w - h4.w) + b4.w + u3.w) * hh.w;
    }
  }

  const int tm = t & 7, tn = (t >> 3) * 2;
  float acc0 = 0.f, acc1 = 0.f;
  for (int k0 = 0; k0 < DDIM; k0 += 64) {
    __syncthreads();
    {
      const int bj = t >> 4, bk = (t & 15) * 4;
#pragma unroll
      for (int i = 0; i < 4; ++i) {
        const int j = bj + i * 16;
        const float4 v =
            *reinterpret_cast<const float4*>(w5u + (size_t)(j0 + j) * DDIM + k0 + bk);
        sB[(bk + 0) * 68 + j] = v.x; sB[(bk + 1) * 68 + j] = v.y;
        sB[(bk + 2) * 68 + j] = v.z; sB[(bk + 3) * 68 + j] = v.w;
      }
    }
    __syncthreads();
#pragma unroll 8
    for (int kk = 0; kk < 64; ++kk) {
      const float a = sA[(k0 + kk) * 9 + tm];
      const float2 b = *reinterpret_cast<const float2*>(sB + kk * 68 + tn);
      acc0 = fmaf(a, b.x, acc0);
      acc1 = fmaf(a, b.y, acc1);
    }
  }

  const int m = m0 + tm;
  float res[2];
#pragma unroll
  for (int jj = 0; jj < 2; ++jj) {
    const int j = j0 + tn + jj;
    const int idx = m * DDIM + j;
    const float a = (jj == 0) ? acc0 : acc1;
    const float hv = tanhf_(fac * (sv35[64 + tn + jj] - hw5[idx]) + b5w[j] + a + b5u[j]);
    const float zv = sigf(fac * (sv35[tn + jj] - hw3[idx]) + b3w[j] + hu3[idx]);
    const float hp = H[idx];
    res[jj] = (1.f - zv) * hp + zv * hv;
  }
  *reinterpret_cast<float2*>(Hn + m * DDIM + j0 + tn) = make_float2(res[0], res[1]);
}

// ---------------------------------------------------------------------------
// O = relu([H|X]*wo^T + bo). 128 thr, tile 8x64, micro 2x2, K=1024.
// grid (32,8)=256. Odd strides 10/66: conflict-light stores, clean reads.
// ---------------------------------------------------------------------------
__global__ void __launch_bounds__(128) k_out(const float* __restrict__ H,
                                             const float* __restrict__ X,
                                             const float* __restrict__ wo,
                                             const float* __restrict__ bo,
                                             float* __restrict__ O) {
  __shared__ float sA[64 * 10];  // [k][8 m + 2]
  __shared__ float sB[64 * 66];  // [k][64 j + 2]
  const int t = threadIdx.x;
  const int m0 = blockIdx.x * 8;
  const int j0 = blockIdx.y * 64;
  const int am = t >> 4, ak = (t & 15) * 4;
  const int bj = t >> 4, bk = (t & 15) * 4;
  const int tm = (t & 3) * 2, tn = (t >> 2) * 2;
  float acc[2][2] = {{0.f, 0.f}, {0.f, 0.f}};

  for (int k0 = 0; k0 < 2 * DDIM; k0 += 64) {
    {
      const float* src = (k0 < DDIM) ? (H + (size_t)(m0 + am) * DDIM + k0 + ak)
                                     : (X + (size_t)(m0 + am) * DDIM + (k0 - DDIM) + ak);
      const float4 v = *reinterpret_cast<const float4*>(src);
      sA[(ak + 0) * 10 + am] = v.x; sA[(ak + 1) * 10 + am] = v.y;
      sA[(ak + 2) * 10 + am] = v.z; sA[(ak + 3) * 10 + am] = v.w;
    }
#pragma unroll
    for (int i = 0; i < 8; ++i) {
      const int jl = bj + 8 * i;
      const float4 v =
          *reinterpret_cast<const float4*>(wo + (size_t)(j0 + jl) * 1024 + k0 + bk);
      sB[(bk + 0) * 66 + jl] = v.x; sB[(bk + 1) * 66 + jl] = v.y;
      sB[(bk + 2) * 66 + jl] = v.z; sB[(bk + 3) * 66 + jl] = v.w;
    }
    __syncthreads();
#pragma unroll 8
    for (int kk = 0; kk < 64; ++kk) {
      const float2 a = *reinterpret_cast<const float2*>(sA + kk * 10 + tm);
      const float2 b = *reinterpret_cast<const float2*>(sB + kk * 66 + tn);
      acc[0][0] = fmaf(a.x, b.x, acc[0][0]); acc[0][1] = fmaf(a.x, b.y, acc[0][1]);
      acc[1][0] = fmaf(a.y, b.x, acc[1][0]); acc[1][1] = fmaf(a.y, b.y, acc[1][1]);
    }
    __syncthreads();
  }
  const int j = j0 + tn;
  const float2 bb = *reinterpret_cast<const float2*>(bo + j);
#pragma unroll
  for (int r = 0; r < 2; ++r) {
    *reinterpret_cast<float2*>(O + (size_t)(m0 + tm + r) * DDIM + j) =
        make_float2(fmaxf(acc[r][0] + bb.x, 0.f), fmaxf(acc[r][1] + bb.y, 0.f));
  }
}

// ---------------------------------------------------------------------------
// obj = O*Wcs^T + bc. Tile 8x32 (N=151 guarded). grid (32,5)=160.
// ---------------------------------------------------------------------------
__global__ void __launch_bounds__(256) k_obj(const float* __restrict__ O,
                                             const float* __restrict__ Wcs,
                                             const float* __restrict__ bc,
                                             float* __restrict__ out) {
  __shared__ float sA[64 * 9];
  __shared__ float sB[64 * 36];
  const int t = threadIdx.x;
  const int m0 = blockIdx.x * 8;
  const int j0 = blockIdx.y * 32;
  const int tm = t & 7, tn = t >> 3;
  float acc = 0.f;
  for (int k0 = 0; k0 < DDIM; k0 += 64) {
    __syncthreads();
    {
      const int r = t >> 5, kp = (t & 31) * 2;
      const float2 v = *reinterpret_cast<const float2*>(O + (m0 + r) * DDIM + k0 + kp);
      sA[(kp + 0) * 9 + r] = v.x; sA[(kp + 1) * 9 + r] = v.y;
      const int bj = t >> 4, bk = (t & 15) * 4;
#pragma unroll
      for (int i = 0; i < 2; ++i) {
        const int j = bj + i * 16;
        const int jg = j0 + j;
        float4 v2 = make_float4(0.f, 0.f, 0.f, 0.f);
        if (jg < CNUM)
          v2 = *reinterpret_cast<const float4*>(Wcs + (size_t)jg * DDIM + k0 + bk);
        sB[(bk + 0) * 36 + j] = v2.x; sB[(bk + 1) * 36 + j] = v2.y;
        sB[(bk + 2) * 36 + j] = v2.z; sB[(bk + 3) * 36 + j] = v2.w;
      }
    }
    __syncthreads();
#pragma unroll 8
    for (int kk = 0; kk < 64; ++kk)
      acc = fmaf(sA[kk * 9 + tm], sB[kk * 36 + tn], acc);
  }
  const int jg = j0 + tn;
  if (jg < CNUM) out[(m0 + tm) * CNUM + jg] = acc + bc[jg];
}

extern "C" void kernel_launch(void* const* d_in, const int* in_sizes, int n_in,
                              void* d_out, int out_size, void* d_ws, size_t ws_size,
                              hipStream_t stream) {
  const float* X = (const float*)d_in[0];
  const float* mat = (const float*)d_in[1];
  const float* w3w = (const float*)d_in[2];
  const float* b3w = (const float*)d_in[3];
  const float* w3u = (const float*)d_in[4];
  const float* b3u = (const float*)d_in[5];
  const float* w4w = (const float*)d_in[6];
  const float* b4w = (const float*)d_in[7];
  // d_in[8], d_in[9] (w4u, b4u) unused — reference reuses w3u/b3u (faithful bug)
  const float* w5w = (const float*)d_in[10];
  const float* b5w = (const float*)d_in[11];
  const float* w5u = (const float*)d_in[12];
  const float* b5u = (const float*)d_in[13];
  const float* wo = (const float*)d_in[14];
  const float* bo = (const float*)d_in[15];
  const float* wc = (const float*)d_in[16];
  const float* bc = (const float*)d_in[17];
  float* out = (float*)d_out;
  float* ws = (float*)d_ws;

  // workspace (floats)
  float* Wcs = ws;                 // 151*512      = 77312
  float* hw = Wcs + 77312;         // 4*256*512    = 524288 (hw3,hw4,hw5,hu3)
  float* psum = hw + 524288;       // 3*8*512      = 12288
  float* H0 = psum + 12288;        // 131072
  float* H1 = H0 + 131072;         // 131072
  float* Obuf = H1 + 131072;       // 131072

  k_wcs<<<CNUM, 256, 0, stream>>>(wc, Wcs);

  const float* Hc = X;  // t=0 hidden = broadcast input (c-uniform collapse)
  float* Hn = H0;
  for (int it = 0; it < 3; ++it) {
    k_G1<<<dim3(8, 32), 256, 0, stream>>>(Hc, w3w, w4w, w5w, w3u, b3u, hw, psum);
    k_G2<<<dim3(32, 8), 256, 0, stream>>>(Hc, hw, psum, mat, b3w, b4w, b5w, w5u, b5u, Hn);
    Hc = Hn;
    Hn = (Hc == H0) ? H1 : H0;
  }
  k_out<<<dim3(32, 8), 128, 0, stream>>>(Hc, X, wo, bo, Obuf);
  k_obj<<<dim3(32, 5), 256, 0, stream>>>(Obuf, Wcs, bc, out);
}

// Round 5
// 158.820 us; speedup vs baseline: 3.3735x; 1.1302x over previous
//
#include <hip/hip_runtime.h>
#include <cmath>

constexpr int NOBJ = 256, CNUM = 151, DDIM = 512;

__device__ __forceinline__ float sigf(float x) { return 1.0f / (1.0f + __expf(-x)); }
__device__ __forceinline__ float tanhf_(float x) {
  float e = __expf(-2.0f * fabsf(x));
  float y = (1.0f - e) / (1.0f + e);
  return copysignf(y, x);
}
__device__ __forceinline__ float4 ld4(const float* p) {
  return *reinterpret_cast<const float4*>(p);
}

// ---------------------------------------------------------------------------
// Wcs[co][d] = sum_c wc[co][c*512+d].  grid (151,4): all CUs stream 46.7 MB.
// ---------------------------------------------------------------------------
__global__ void __launch_bounds__(256) k_wcs(const float* __restrict__ wc,
                                             float* __restrict__ Wcs) {
  const int co = blockIdx.x, q = blockIdx.y, t = threadIdx.x;
  const int d = q * 128 + (t & 31) * 4;
  const int g = t >> 5;  // 8-way c-split
  const float* row = wc + (size_t)co * (CNUM * DDIM);
  float4 s = make_float4(0.f, 0.f, 0.f, 0.f);
  for (int c = g; c < CNUM; c += 8) {
    const float4 v = ld4(row + c * DDIM + d);
    s.x += v.x; s.y += v.y; s.z += v.z; s.w += v.w;
  }
  __shared__ float4 red[256];
  red[t] = s;
  __syncthreads();
  if (t < 128) { red[t].x += red[t+128].x; red[t].y += red[t+128].y;
                 red[t].z += red[t+128].z; red[t].w += red[t+128].w; }
  __syncthreads();
  if (t < 64)  { red[t].x += red[t+64].x; red[t].y += red[t+64].y;
                 red[t].z += red[t+64].z; red[t].w += red[t+64].w; }
  __syncthreads();
  if (t < 32) {
    float4 o = red[t];
    o.x += red[t+32].x; o.y += red[t+32].y; o.z += red[t+32].z; o.w += red[t+32].w;
    *reinterpret_cast<float4*>(Wcs + co * DDIM + q * 128 + t * 4) = o;
  }
}

// ---------------------------------------------------------------------------
// G1: hw_z = H*Wsum_z^T (fold on the fly), hu3 = H*w3u^T + b3u.
// Tile 32(m) x 32(j), micro 2x2, grid (8, 64) = 512 blocks (2/CU).
// Reg-prefetch double-buffer: issue chunk c+1 global loads before compute(c).
// Epilogue: psum[z][8][512] column partials via intra-wave shfl.
// ---------------------------------------------------------------------------
__global__ void __launch_bounds__(256) k_G1(
    const float* __restrict__ H, const float* __restrict__ w3w,
    const float* __restrict__ w4w, const float* __restrict__ w5w,
    const float* __restrict__ w3u, const float* __restrict__ b3u,
    float* __restrict__ hw, float* __restrict__ psum) {
  __shared__ float sA[64 * 34];  // [k][32 m + 2]
  __shared__ float sB[64 * 34];  // [k][32 j + 2]
  const int t = threadIdx.x;
  const int m0 = blockIdx.x * 32;
  const int z = blockIdx.y >> 4;
  const int j0 = (blockIdx.y & 15) * 32;
  const float* W = (z == 0) ? w3w : (z == 1) ? w4w : (z == 2) ? w5w : w3u;
  const int am = t >> 3, ak = (t & 7) * 8;  // A: row am, 8 k's
  const int bj = t >> 3, bk = (t & 7) * 8;  // B: row bj, 8 k's
  const int tm = (t & 15) * 2, tn = (t >> 4) * 2;
  float acc[2][2] = {{0.f, 0.f}, {0.f, 0.f}};
  float4 ra0, ra1, rb0, rb1, rb2, rb3;

#define G1_LOAD(k0)                                                     \
  {                                                                     \
    const float* as = H + (size_t)(m0 + am) * DDIM + (k0) + ak;         \
    ra0 = ld4(as); ra1 = ld4(as + 4);                                   \
    if (z < 3) {                                                        \
      const float* bs = W + (size_t)(j0 + bj) * 1024 + (k0) + bk;       \
      rb0 = ld4(bs); rb1 = ld4(bs + 4);                                 \
      rb2 = ld4(bs + 512); rb3 = ld4(bs + 516);                         \
    } else {                                                            \
      const float* bs = W + (size_t)(j0 + bj) * DDIM + (k0) + bk;       \
      rb0 = ld4(bs); rb1 = ld4(bs + 4);                                 \
    }                                                                   \
  }

  G1_LOAD(0);
  for (int c = 0; c < 8; ++c) {
    __syncthreads();
    sA[(ak + 0) * 34 + am] = ra0.x; sA[(ak + 1) * 34 + am] = ra0.y;
    sA[(ak + 2) * 34 + am] = ra0.z; sA[(ak + 3) * 34 + am] = ra0.w;
    sA[(ak + 4) * 34 + am] = ra1.x; sA[(ak + 5) * 34 + am] = ra1.y;
    sA[(ak + 6) * 34 + am] = ra1.z; sA[(ak + 7) * 34 + am] = ra1.w;
    if (z < 3) {
      sB[(bk + 0) * 34 + bj] = rb0.x + rb2.x; sB[(bk + 1) * 34 + bj] = rb0.y + rb2.y;
      sB[(bk + 2) * 34 + bj] = rb0.z + rb2.z; sB[(bk + 3) * 34 + bj] = rb0.w + rb2.w;
      sB[(bk + 4) * 34 + bj] = rb1.x + rb3.x; sB[(bk + 5) * 34 + bj] = rb1.y + rb3.y;
      sB[(bk + 6) * 34 + bj] = rb1.z + rb3.z; sB[(bk + 7) * 34 + bj] = rb1.w + rb3.w;
    } else {
      sB[(bk + 0) * 34 + bj] = rb0.x; sB[(bk + 1) * 34 + bj] = rb0.y;
      sB[(bk + 2) * 34 + bj] = rb0.z; sB[(bk + 3) * 34 + bj] = rb0.w;
      sB[(bk + 4) * 34 + bj] = rb1.x; sB[(bk + 5) * 34 + bj] = rb1.y;
      sB[(bk + 6) * 34 + bj] = rb1.z; sB[(bk + 7) * 34 + bj] = rb1.w;
    }
    __syncthreads();
    if (c < 7) G1_LOAD((c + 1) * 64);  // in flight during compute below
#pragma unroll 8
    for (int kk = 0; kk < 64; ++kk) {
      const float2 a = *reinterpret_cast<const float2*>(sA + kk * 34 + tm);
      const float2 b = *reinterpret_cast<const float2*>(sB + kk * 34 + tn);
      acc[0][0] = fmaf(a.x, b.x, acc[0][0]); acc[0][1] = fmaf(a.x, b.y, acc[0][1]);
      acc[1][0] = fmaf(a.y, b.x, acc[1][0]); acc[1][1] = fmaf(a.y, b.y, acc[1][1]);
    }
  }
#undef G1_LOAD

  float* op = hw + (size_t)z * (NOBJ * DDIM);
  float2 bias = make_float2(0.f, 0.f);
  if (z == 3) bias = *reinterpret_cast<const float2*>(b3u + j0 + tn);
#pragma unroll
  for (int r = 0; r < 2; ++r)
    *reinterpret_cast<float2*>(op + (size_t)(m0 + tm + r) * DDIM + j0 + tn) =
        make_float2(acc[r][0] + bias.x, acc[r][1] + bias.y);

  if (z < 3) {  // deterministic column sums over the block's 32 rows
    float s0 = acc[0][0] + acc[1][0];
    float s1 = acc[0][1] + acc[1][1];
#pragma unroll
    for (int mask = 1; mask < 16; mask <<= 1) {  // reduce over t&15 (m-positions)
      s0 += __shfl_xor(s0, mask, 64);
      s1 += __shfl_xor(s1, mask, 64);
    }
    if ((t & 15) == 0)
      *reinterpret_cast<float2*>(psum + z * 4096 + blockIdx.x * 512 + j0 + tn) =
          make_float2(s0, s1);
  }
}

// ---------------------------------------------------------------------------
// G2g: split-K GEMM P5[s] = (rv ⊙ H) * w5u^T over K-half s.
// rv = sig(fac*(svh4-hw4)+b4w+hu3). Tile 8x64, grid (32,8,2) = 512 blocks.
// ---------------------------------------------------------------------------
__global__ void __launch_bounds__(256) k_G2g(
    const float* __restrict__ H, const float* __restrict__ hw,
    const float* __restrict__ psum, const float* __restrict__ mat,
    const float* __restrict__ b4w, const float* __restrict__ w5u,
    float* __restrict__ P5) {
  __shared__ float sA[256 * 9];  // rvH K-half, [k][8 m + 1]
  __shared__ float sB[64 * 66];  // w5u chunk [k][64 j + 2]
  __shared__ float sv4[256];
  const int t = threadIdx.x;
  const int m0 = blockIdx.x * 8;
  const int j0 = blockIdx.y * 64;
  const int s = blockIdx.z;
  const float fac = mat[0] * (float)CNUM;
  const float* hw4 = hw + NOBJ * DDIM;
  const float* hu3 = hw + 3 * NOBJ * DDIM;

  {  // svh4 for this K-half
    const int k = s * 256 + t;
    float a = 0.f;
#pragma unroll
    for (int mt = 0; mt < 8; ++mt) a += psum[4096 + mt * 512 + k];
    sv4[t] = a;
  }
  __syncthreads();
  {  // stage rv ⊙ H for 8 rows x 256 k
    const int m = t >> 5, kq = (t & 31) * 8;
    const int idx = (m0 + m) * DDIM + s * 256 + kq;
    const float4 h4a = ld4(hw4 + idx), h4b = ld4(hw4 + idx + 4);
    const float4 u3a = ld4(hu3 + idx), u3b = ld4(hu3 + idx + 4);
    const float4 hha = ld4(H + idx), hhb = ld4(H + idx + 4);
    const float4 b4a = ld4(b4w + s * 256 + kq), b4b = ld4(b4w + s * 256 + kq + 4);
    const float4 s4a = ld4(sv4 + kq), s4b = ld4(sv4 + kq + 4);
    sA[(kq + 0) * 9 + m] = sigf(fac * (s4a.x - h4a.x) + b4a.x + u3a.x) * hha.x;
    sA[(kq + 1) * 9 + m] = sigf(fac * (s4a.y - h4a.y) + b4a.y + u3a.y) * hha.y;
    sA[(kq + 2) * 9 + m] = sigf(fac * (s4a.z - h4a.z) + b4a.z + u3a.z) * hha.z;
    sA[(kq + 3) * 9 + m] = sigf(fac * (s4a.w - h4a.w) + b4a.w + u3a.w) * hha.w;
    sA[(kq + 4) * 9 + m] = sigf(fac * (s4b.x - h4b.x) + b4b.x + u3b.x) * hhb.x;
    sA[(kq + 5) * 9 + m] = sigf(fac * (s4b.y - h4b.y) + b4b.y + u3b.y) * hhb.y;
    sA[(kq + 6) * 9 + m] = sigf(fac * (s4b.z - h4b.z) + b4b.z + u3b.z) * hhb.z;
    sA[(kq + 7) * 9 + m] = sigf(fac * (s4b.w - h4b.w) + b4b.w + u3b.w) * hhb.w;
  }

  const int bj = t >> 2, bk = (t & 3) * 16;  // B: row bj, 16 k's
  const int tm = t & 7, tn = (t >> 3) * 2;
  float acc0 = 0.f, acc1 = 0.f;
  float4 rb[4];
#define G2_LOADB(c)                                                        \
  {                                                                        \
    const float* bs = w5u + (size_t)(j0 + bj) * DDIM + s * 256 + (c) * 64 + bk; \
    rb[0] = ld4(bs); rb[1] = ld4(bs + 4); rb[2] = ld4(bs + 8); rb[3] = ld4(bs + 12); \
  }
  G2_LOADB(0);
  for (int c = 0; c < 4; ++c) {
    __syncthreads();
#pragma unroll
    for (int i = 0; i < 4; ++i) {
      sB[(bk + i * 4 + 0) * 66 + bj] = rb[i].x;
      sB[(bk + i * 4 + 1) * 66 + bj] = rb[i].y;
      sB[(bk + i * 4 + 2) * 66 + bj] = rb[i].z;
      sB[(bk + i * 4 + 3) * 66 + bj] = rb[i].w;
    }
    __syncthreads();
    if (c < 3) G2_LOADB(c + 1);
#pragma unroll 8
    for (int kk = 0; kk < 64; ++kk) {
      const float a = sA[(c * 64 + kk) * 9 + tm];
      const float2 b = *reinterpret_cast<const float2*>(sB + kk * 66 + tn);
      acc0 = fmaf(a, b.x, acc0);
      acc1 = fmaf(a, b.y, acc1);
    }
  }
#undef G2_LOADB
  *reinterpret_cast<float2*>(P5 + (size_t)s * (NOBJ * DDIM) + (m0 + tm) * DDIM + j0 + tn) =
      make_float2(acc0, acc1);
}

// ---------------------------------------------------------------------------
// upd: Hn = (1-zv)*H + zv*tanh(hpre + P0+P1 + b5u), zv = sig(zpre).
// grid 512 = 32 m-blocks(8) x 16 j-blocks(32); svh3/5 staged in LDS per block.
// ---------------------------------------------------------------------------
__global__ void __launch_bounds__(256) k_upd(
    const float* __restrict__ H, const float* __restrict__ hw,
    const float* __restrict__ psum, const float* __restrict__ P5,
    const float* __restrict__ mat, const float* __restrict__ b3w,
    const float* __restrict__ b5w, const float* __restrict__ b5u,
    float* __restrict__ Hn) {
  __shared__ float s3[32], s5[32];
  const int t = threadIdx.x;
  const int m0 = (blockIdx.x >> 4) * 8;
  const int j0 = (blockIdx.x & 15) * 32;
  const float fac = mat[0] * (float)CNUM;
  const float* hw3 = hw;
  const float* hw5 = hw + 2 * NOBJ * DDIM;
  const float* hu3 = hw + 3 * NOBJ * DDIM;
  if (t < 32) {
    const int j = j0 + t;
    float a = 0.f, b = 0.f;
#pragma unroll
    for (int mt = 0; mt < 8; ++mt) {
      a += psum[mt * 512 + j];
      b += psum[2 * 4096 + mt * 512 + j];
    }
    s3[t] = a; s5[t] = b;
  }
  __syncthreads();
  const int r = t >> 5, c = t & 31;
  const int m = m0 + r, j = j0 + c;
  const int idx = m * DDIM + j;
  const float p = P5[idx] + P5[NOBJ * DDIM + idx];
  const float hv = tanhf_(fac * (s5[c] - hw5[idx]) + b5w[j] + p + b5u[j]);
  const float zv = sigf(fac * (s3[c] - hw3[idx]) + b3w[j] + hu3[idx]);
  Hn[idx] = (1.f - zv) * H[idx] + zv * hv;
}

// ---------------------------------------------------------------------------
// out partials: Po[s] = (s?X:H) * wo[:, s*512:(s+1)*512]^T  (split at concat!)
// Tile 8x64, grid (32,8,2) = 512 blocks. No bias/relu (fused into k_obj).
// ---------------------------------------------------------------------------
__global__ void __launch_bounds__(256) k_out(const float* __restrict__ H,
                                             const float* __restrict__ X,
                                             const float* __restrict__ wo,
                                             float* __restrict__ Po) {
  __shared__ float sA[512 * 9];  // K-half resident, [k][8 m + 1]
  __shared__ float sB[64 * 66];
  const int t = threadIdx.x;
  const int m0 = blockIdx.x * 8;
  const int j0 = blockIdx.y * 64;
  const int s = blockIdx.z;
  const float* A = s ? X : H;
  {  // stage A: 8 rows x 512 k
    const int m = t >> 5, kq = (t & 31) * 16;
    const float* src = A + (size_t)(m0 + m) * DDIM + kq;
#pragma unroll
    for (int i = 0; i < 4; ++i) {
      const float4 v = ld4(src + i * 4);
      sA[(kq + i * 4 + 0) * 9 + m] = v.x; sA[(kq + i * 4 + 1) * 9 + m] = v.y;
      sA[(kq + i * 4 + 2) * 9 + m] = v.z; sA[(kq + i * 4 + 3) * 9 + m] = v.w;
    }
  }
  const int bj = t >> 2, bk = (t & 3) * 16;
  const int tm = t & 7, tn = (t >> 3) * 2;
  float acc0 = 0.f, acc1 = 0.f;
  float4 rb[4];
#define KO_LOADB(c)                                                         \
  {                                                                         \
    const float* bs = wo + (size_t)(j0 + bj) * 1024 + s * 512 + (c) * 64 + bk; \
    rb[0] = ld4(bs); rb[1] = ld4(bs + 4); rb[2] = ld4(bs + 8); rb[3] = ld4(bs + 12); \
  }
  KO_LOADB(0);
  for (int c = 0; c < 8; ++c) {
    __syncthreads();
#pragma unroll
    for (int i = 0; i < 4; ++i) {
      sB[(bk + i * 4 + 0) * 66 + bj] = rb[i].x;
      sB[(bk + i * 4 + 1) * 66 + bj] = rb[i].y;
      sB[(bk + i * 4 + 2) * 66 + bj] = rb[i].z;
      sB[(bk + i * 4 + 3) * 66 + bj] = rb[i].w;
    }
    __syncthreads();
    if (c < 7) KO_LOADB(c + 1);
#pragma unroll 8
    for (int kk = 0; kk < 64; ++kk) {
      const float a = sA[(c * 64 + kk) * 9 + tm];
      const float2 b = *reinterpret_cast<const float2*>(sB + kk * 66 + tn);
      acc0 = fmaf(a, b.x, acc0);
      acc1 = fmaf(a, b.y, acc1);
    }
  }
#undef KO_LOADB
  *reinterpret_cast<float2*>(Po + (size_t)s * (NOBJ * DDIM) + (m0 + tm) * DDIM + j0 + tn) =
      make_float2(acc0, acc1);
}

// ---------------------------------------------------------------------------
// obj = relu(Po0+Po1+bo) * Wcs^T + bc. Tile 8x32 (N=151 guarded). grid (32,5).
// ---------------------------------------------------------------------------
__global__ void __launch_bounds__(256) k_obj(const float* __restrict__ Po,
                                             const float* __restrict__ bo,
                                             const float* __restrict__ Wcs,
                                             const float* __restrict__ bc,
                                             float* __restrict__ out) {
  __shared__ float sA[64 * 9];
  __shared__ float sB[64 * 36];
  const int t = threadIdx.x;
  const int m0 = blockIdx.x * 8;
  const int j0 = blockIdx.y * 32;
  const int tm = t & 7, tn = t >> 3;
  float acc = 0.f;
  for (int k0 = 0; k0 < DDIM; k0 += 64) {
    __syncthreads();
    {
      const int r = t >> 5, kp = (t & 31) * 2;
      const int idx = (m0 + r) * DDIM + k0 + kp;
      const float2 o0 = *reinterpret_cast<const float2*>(Po + idx);
      const float2 o1 = *reinterpret_cast<const float2*>(Po + NOBJ * DDIM + idx);
      const float2 bb = *reinterpret_cast<const float2*>(bo + k0 + kp);
      sA[(kp + 0) * 9 + r] = fmaxf(o0.x + o1.x + bb.x, 0.f);
      sA[(kp + 1) * 9 + r] = fmaxf(o0.y + o1.y + bb.y, 0.f);
      const int bj = t >> 4, bk = (t & 15) * 4;
#pragma unroll
      for (int i = 0; i < 2; ++i) {
        const int j = bj + i * 16;
        const int jg = j0 + j;
        float4 v2 = make_float4(0.f, 0.f, 0.f, 0.f);
        if (jg < CNUM) v2 = ld4(Wcs + (size_t)jg * DDIM + k0 + bk);
        sB[(bk + 0) * 36 + j] = v2.x; sB[(bk + 1) * 36 + j] = v2.y;
        sB[(bk + 2) * 36 + j] = v2.z; sB[(bk + 3) * 36 + j] = v2.w;
      }
    }
    __syncthreads();
#pragma unroll 8
    for (int kk = 0; kk < 64; ++kk)
      acc = fmaf(sA[kk * 9 + tm], sB[kk * 36 + tn], acc);
  }
  const int jg = j0 + tn;
  if (jg < CNUM) out[(m0 + tm) * CNUM + jg] = acc + bc[jg];
}

extern "C" void kernel_launch(void* const* d_in, const int* in_sizes, int n_in,
                              void* d_out, int out_size, void* d_ws, size_t ws_size,
                              hipStream_t stream) {
  const float* X = (const float*)d_in[0];
  const float* mat = (const float*)d_in[1];
  const float* w3w = (const float*)d_in[2];
  const float* b3w = (const float*)d_in[3];
  const float* w3u = (const float*)d_in[4];
  const float* b3u = (const float*)d_in[5];
  const float* w4w = (const float*)d_in[6];
  const float* b4w = (const float*)d_in[7];
  // d_in[8], d_in[9] (w4u, b4u) unused — reference reuses w3u/b3u (faithful bug)
  const float* w5w = (const float*)d_in[10];
  const float* b5w = (const float*)d_in[11];
  const float* w5u = (const float*)d_in[12];
  const float* b5u = (const float*)d_in[13];
  const float* wo = (const float*)d_in[14];
  const float* bo = (const float*)d_in[15];
  const float* wc = (const float*)d_in[16];
  const float* bc = (const float*)d_in[17];
  float* out = (float*)d_out;
  float* ws = (float*)d_ws;

  // workspace (floats): ~5.6 MB
  float* Wcs = ws;               // 151*512    = 77312
  float* hw = Wcs + 77312;       // 4*256*512  = 524288 (hw3,hw4,hw5,hu3)
  float* psum = hw + 524288;     // 3*8*512    = 12288
  float* H0 = psum + 12288;      // 131072
  float* H1 = H0 + 131072;       // 131072
  float* P5 = H1 + 131072;       // 2*131072
  float* Po = P5 + 262144;       // 2*131072

  k_wcs<<<dim3(CNUM, 4), 256, 0, stream>>>(wc, Wcs);

  const float* Hc = X;  // t=0 hidden = broadcast input (c-uniform collapse)
  float* Hn = H0;
  for (int it = 0; it < 3; ++it) {
    k_G1<<<dim3(8, 64), 256, 0, stream>>>(Hc, w3w, w4w, w5w, w3u, b3u, hw, psum);
    k_G2g<<<dim3(32, 8, 2), 256, 0, stream>>>(Hc, hw, psum, mat, b4w, w5u, P5);
    k_upd<<<512, 256, 0, stream>>>(Hc, hw, psum, P5, mat, b3w, b5w, b5u, Hn);
    Hc = Hn;
    Hn = (Hc == H0) ? H1 : H0;
  }
  k_out<<<dim3(32, 8, 2), 256, 0, stream>>>(Hc, X, wo, Po);
  k_obj<<<dim3(32, 5), 256, 0, stream>>>(Po, bo, Wcs, bc, out);
}